// Round 1
// baseline (1355.009 us; speedup 1.0000x reference)
//
#include <hip/hip_runtime.h>

#define N_   32
#define DIM_ 256
#define T_   120
#define V_   25
#define H_   8
#define HD_  32
#define SCALE_ 0.17677669529663687f   // 32^-0.5

// Fully fused per-(n,t) kernel. 256 threads/block, f32 throughout.
// LDS budget: xs 26000 + (q,k,v,e) 4*7200 + A 2600 + R 800 + bias 128 + oh 3584
//           = 61912 B  (<64 KiB, 2 blocks/CU)
__launch_bounds__(256, 2)
__global__ void mhsa_fused(const float* __restrict__ x,
                           const float* __restrict__ e,
                           const float* __restrict__ Wkv,
                           const float* __restrict__ Wq,
                           const float* __restrict__ Wproj,
                           const float* __restrict__ bproj,
                           const float* __restrict__ rpe,
                           const float* __restrict__ w1,
                           const float* __restrict__ outer,
                           const float* __restrict__ alpha,
                           float* __restrict__ out)
{
    const int tid = threadIdx.x;
    const int nt  = blockIdx.x;
    const int n   = nt / T_;
    const int t   = nt % T_;

    __shared__ float xs[V_][260];        // x tile transposed: xs[v][c], pitch 260 (16B-aligned rows)
    __shared__ float q_l[2][V_][36];     // per head-pair: q[a][hd]
    __shared__ float k_l[2][V_][36];
    __shared__ float v_l[2][V_][36];
    __shared__ float e_l[2][V_][36];     // e_k[b][hd]
    __shared__ float A_l[V_][26];        // scores -> softmax -> G
    __shared__ float R_l[V_][8];         // q . rpe[j]  (j = 0..4)
    __shared__ float bias_l[32];         // w1 . e_k[b]
    __shared__ float oh_t[HD_][28];      // attention out, transposed [hd][a]

    const float alpha0 = alpha[0];

    // ---- load x tile (transposed) ----
    const float* xbase = x + ((size_t)n * DIM_ * T_ + t) * V_;
    for (int i = tid; i < DIM_ * V_; i += 256) {
        int c = i / V_, v = i % V_;
        xs[v][c] = xbase[(size_t)c * (T_ * V_) + v];
    }

    // persistent per-thread output accumulator: thread owns channel d = tid, all 25 nodes
    float accv[28];
    #pragma unroll
    for (int i = 0; i < 28; ++i) accv[i] = 0.f;

    const float* ebase = e + ((size_t)n * DIM_ * T_ + t) * V_;

    for (int hp = 0; hp < 4; ++hp) {          // head pairs: heads 2*hp, 2*hp+1
        __syncthreads();

        // ---- load e_k for both heads of the pair ----
        for (int i = tid; i < 1600; i += 256) {
            int ph = i / 800, r = i % 800;
            int hd = r / 25, b = r % 25;
            e_l[ph][b][hd] = ebase[(size_t)((hp * 2 + ph) * HD_ + hd) * (T_ * V_) + b];
        }

        // ---- GEMM: q,k,v for 2 heads (192 rows x 25 cols), 4x5 register tiles ----
        if (tid < 240) {
            const int rt = tid / 5, ct = tid % 5;
            const int R0 = rt * 4;
            const int ph   = R0 / 96;
            const int rr   = R0 % 96;
            const int type = rr >> 5;          // 0=q 1=k 2=v
            const int hd0  = rr & 31;
            const int head = hp * 2 + ph;
            const float* wbase;
            if (type == 0)      wbase = Wq  + (size_t)(head * HD_ + hd0) * DIM_;
            else if (type == 1) wbase = Wkv + (size_t)(head * HD_ + hd0) * DIM_;
            else                wbase = Wkv + (size_t)(DIM_ + head * HD_ + hd0) * DIM_;

            float acc[4][5];
            #pragma unroll
            for (int i = 0; i < 4; ++i)
                #pragma unroll
                for (int j = 0; j < 5; ++j) acc[i][j] = 0.f;

            for (int c = 0; c < DIM_; c += 4) {
                float4 xv[5];
                #pragma unroll
                for (int j = 0; j < 5; ++j)
                    xv[j] = *(const float4*)&xs[ct * 5 + j][c];
                #pragma unroll
                for (int i = 0; i < 4; ++i) {
                    float4 wv = *(const float4*)&wbase[(size_t)i * DIM_ + c];
                    #pragma unroll
                    for (int j = 0; j < 5; ++j)
                        acc[i][j] += wv.x * xv[j].x + wv.y * xv[j].y
                                   + wv.z * xv[j].z + wv.w * xv[j].w;
                }
            }
            float (*dst)[V_][36] = (type == 0) ? q_l : (type == 1) ? k_l : v_l;
            #pragma unroll
            for (int i = 0; i < 4; ++i)
                #pragma unroll
                for (int j = 0; j < 5; ++j)
                    dst[ph][ct * 5 + j][hd0 + i] = acc[i][j];
        }
        __syncthreads();

        for (int ph = 0; ph < 2; ++ph) {
            const int h = hp * 2 + ph;

            // ---- scores (content + group), rpe dots, group bias ----
            for (int i = tid; i < 775; i += 256) {
                if (i < 625) {
                    int a = i / 25, b = i % 25;
                    float s = 0.f;
                    #pragma unroll
                    for (int cq = 0; cq < 8; ++cq) {
                        float4 qv = *(const float4*)&q_l[ph][a][cq * 4];
                        float4 kv = *(const float4*)&k_l[ph][b][cq * 4];
                        float4 ev = *(const float4*)&e_l[ph][b][cq * 4];
                        s += qv.x * (kv.x + ev.x) + qv.y * (kv.y + ev.y)
                           + qv.z * (kv.z + ev.z) + qv.w * (kv.w + ev.w);
                    }
                    A_l[a][b] = s;
                } else if (i < 750) {
                    int idx = i - 625;
                    int a = idx / 5, j = idx % 5;
                    const float* rp = rpe + j * DIM_ + h * HD_;
                    float s = 0.f;
                    #pragma unroll
                    for (int cq = 0; cq < 8; ++cq) {
                        float4 qv = *(const float4*)&q_l[ph][a][cq * 4];
                        float4 rv = *(const float4*)&rp[cq * 4];
                        s += qv.x * rv.x + qv.y * rv.y + qv.z * rv.z + qv.w * rv.w;
                    }
                    R_l[a][j] = s;
                } else {
                    int b = i - 750;
                    const float* wp1 = w1 + h * HD_;
                    float s = 0.f;
                    #pragma unroll
                    for (int cq = 0; cq < 8; ++cq) {
                        float4 wv = *(const float4*)&wp1[cq * 4];
                        float4 ev = *(const float4*)&e_l[ph][b][cq * 4];
                        s += wv.x * ev.x + wv.y * ev.y + wv.z * ev.z + wv.w * ev.w;
                    }
                    bias_l[b] = s;
                }
            }
            __syncthreads();

            // ---- softmax per query row + fuse (alpha*P + outer) ----
            if (tid < 25) {
                const int a = tid;
                float row[25];
                #pragma unroll
                for (int b = 0; b < 25; ++b) {
                    int d = a - b; if (d < 0) d = -d; if (d > 4) d = 4;  // hops
                    row[b] = (A_l[a][b] + R_l[a][d] + bias_l[b]) * SCALE_;
                }
                float m = row[0];
                #pragma unroll
                for (int b = 1; b < 25; ++b) m = fmaxf(m, row[b]);
                float s = 0.f;
                #pragma unroll
                for (int b = 0; b < 25; ++b) { row[b] = __expf(row[b] - m); s += row[b]; }
                float inv = alpha0 / s;
                const float* ob = outer + ((size_t)h * 25 + a) * 25;
                #pragma unroll
                for (int b = 0; b < 25; ++b) A_l[a][b] = row[b] * inv + ob[b];
            }
            __syncthreads();

            // ---- PV: oh[a][hd] = sum_b G[a][b] * v[b][hd]  (stored transposed) ----
            for (int i = tid; i < 896; i += 256) {
                int a = i >> 5, hd = i & 31;
                float s = 0.f;
                if (a < 25) {
                    #pragma unroll 5
                    for (int b = 0; b < 25; ++b) s += A_l[a][b] * v_l[ph][b][hd];
                }
                oh_t[hd][a] = s;   // cols 25..27 zeroed for padded f4 reads below
            }
            __syncthreads();

            // ---- proj rank-32 accumulate: accv[v] += Wproj[d, h*32+hd] * oh[v][hd] ----
            {
                const float* wpb = Wproj + (size_t)tid * DIM_ + h * HD_;
                float4 wq[8];
                #pragma unroll
                for (int i = 0; i < 8; ++i) wq[i] = *(const float4*)&wpb[i * 4];
                #pragma unroll
                for (int i = 0; i < 8; ++i) {
                    float ws[4] = {wq[i].x, wq[i].y, wq[i].z, wq[i].w};
                    #pragma unroll
                    for (int u = 0; u < 4; ++u) {
                        const int hd = i * 4 + u;
                        #pragma unroll
                        for (int v4 = 0; v4 < 7; ++v4) {
                            float4 o = *(const float4*)&oh_t[hd][v4 * 4];
                            accv[v4 * 4 + 0] += ws[u] * o.x;
                            accv[v4 * 4 + 1] += ws[u] * o.y;
                            accv[v4 * 4 + 2] += ws[u] * o.z;
                            accv[v4 * 4 + 3] += ws[u] * o.w;
                        }
                    }
                }
            }
            __syncthreads();
        }
    }

    // ---- write out: thread d = tid owns row (n, d, t, :) ----
    const float bp = bproj[tid];
    float* ob = out + ((size_t)(n * DIM_ + tid) * T_ + t) * V_;
    #pragma unroll
    for (int v = 0; v < 25; ++v) ob[v] = accv[v] + bp;
}

extern "C" void kernel_launch(void* const* d_in, const int* in_sizes, int n_in,
                              void* d_out, int out_size, void* d_ws, size_t ws_size,
                              hipStream_t stream) {
    (void)in_sizes; (void)n_in; (void)out_size; (void)d_ws; (void)ws_size;
    const float* x     = (const float*)d_in[0];
    const float* e     = (const float*)d_in[1];
    const float* Wkv   = (const float*)d_in[2];
    const float* Wq    = (const float*)d_in[3];
    const float* Wproj = (const float*)d_in[4];
    const float* bproj = (const float*)d_in[5];
    const float* rpe   = (const float*)d_in[6];
    const float* w1    = (const float*)d_in[7];
    const float* outer = (const float*)d_in[8];
    const float* alpha = (const float*)d_in[9];
    // d_in[10] = hops, recomputed inline as min(|a-b|, 4)
    float* out = (float*)d_out;

    mhsa_fused<<<N_ * T_, 256, 0, stream>>>(x, e, Wkv, Wq, Wproj, bproj,
                                            rpe, w1, outer, alpha, out);
}

// Round 2
// 453.256 us; speedup vs baseline: 2.9895x; 2.9895x over previous
//
#include <hip/hip_runtime.h>

typedef __attribute__((ext_vector_type(8))) short bf16x8;
typedef __attribute__((ext_vector_type(4))) float f32x4;
typedef unsigned short u16;
typedef unsigned int u32;

#define SCALE_ 0.17677669529663687f   // 32^-0.5
#define MFMA(a,b,c) __builtin_amdgcn_mfma_f32_16x16x32_bf16(a,b,c,0,0,0)

__device__ __forceinline__ u16 f2bf(float f){
    u32 u = __float_as_uint(f);
    u = (u + 0x7FFFu + ((u >> 16) & 1u)) >> 16;
    return (u16)u;
}
__device__ __forceinline__ float bf2f(u16 h){ return __uint_as_float(((u32)h) << 16); }
__device__ __forceinline__ u32 pk2(float a, float b){ return (u32)f2bf(a) | ((u32)f2bf(b) << 16); }

// Pack weights to bf16 fragment-friendly rows in workspace.
// Rows 0-255: Wq ; 256-767: Wkv (k then v) ; 768-1023: Wproj ; then 5x256 rpe.
__global__ void prep_kernel(const float* __restrict__ Wkv, const float* __restrict__ Wq,
                            const float* __restrict__ Wproj, const float* __restrict__ rpe,
                            u16* __restrict__ wpk)
{
    int i = blockIdx.x * 256 + threadIdx.x;
    if (i < 262144){
        int row = i >> 8, c = i & 255;
        float v;
        if (row < 256)      v = Wq[(row << 8) | c];
        else if (row < 768) v = Wkv[((row - 256) << 8) | c];
        else                v = Wproj[((row - 768) << 8) | c];
        wpk[i] = f2bf(v);
    } else if (i < 263424){
        wpk[i] = f2bf(rpe[i - 262144]);
    }
}

// Fused MFMA kernel: one block = (n, 4 consecutive t). 256 threads = 4 waves.
__launch_bounds__(256, 2)
__global__ void mhsa_main(const float* __restrict__ x, const float* __restrict__ e,
                          const float* __restrict__ w1, const float* __restrict__ outer,
                          const float* __restrict__ alpha, const float* __restrict__ bproj,
                          const u16* __restrict__ wpk, float* __restrict__ out)
{
    // K-packed layouts: [chunk][col][8] so B-fragments are single b128 reads.
    __shared__ u16 xs [32*32*8];   // x tile  [c>>3][v(32)][c&7]
    __shared__ u16 es2[32*26*8];   // e tile  [c>>3][v(26 pitch)][c&7]
    __shared__ u16 qs [2*32*40];   // q [hl][a(32)][hd, pitch 40]   (rows 25-31 stay 0)
    __shared__ u16 ke [2*4*32*8];  // k+e as B: [hl][hd>>3][col: b0-24,rpe25-29,0][hd&7]
    __shared__ u16 vT [2*32*40];   // v^T as A: [hl][hd][b, pitch 40] (cols 25+ stay 0)
    __shared__ u16 GT [2*4*32*8];  // G^T as B: [hl][b>>3][a][b&7]
    __shared__ u16 opk[32*32*8];   // attn out: [c'>>3][a(32)][c'&7]  (cols 25-31 stay 0)
    __shared__ float biasl[64];    // w1 . e_k  per head-local

    const int tid = threadIdx.x;
    const int w = tid >> 6, lane = tid & 63;
    const int l15 = lane & 15, kg = lane >> 4;
    const int n = blockIdx.x / 30, tq = blockIdx.x % 30;
    const float alpha0 = alpha[0];
    const f32x4 zf = {0.f, 0.f, 0.f, 0.f};

    // zero-init regions whose pads must be 0 / stay 0
    for (int i = tid; i < 2560; i += 256){ qs[i] = 0; vT[i] = 0; }
    for (int i = tid; i < 2048; i += 256){ ke[i] = 0; GT[i] = 0; }
    for (int i = tid; i < 8192; i += 256) opk[i] = 0;
    if (tid < 64) biasl[tid] = 0.f;

    for (int tl = 0; tl < 4; ++tl){
        const int t = tq * 4 + tl;
        const float* xb = x + ((size_t)n * 256 * 120 + t) * 25;
        const float* eb = e + ((size_t)n * 256 * 120 + t) * 25;
        for (int i = tid; i < 8192; i += 256){
            int c = i >> 5, vv = i & 31;
            if (vv < 25){
                xs [((c>>3)*32 + vv)*8 + (c&7)] = f2bf(xb[c*3000 + vv]);
                es2[((c>>3)*26 + vv)*8 + (c&7)] = f2bf(eb[c*3000 + vv]);
            }
        }
        __syncthreads();

        for (int hg = 0; hg < 4; ++hg){
            const int hl = w >> 1;          // head-local for this wave
            const int mt = w & 1;           // tile half
            const int h  = hg * 2 + hl;

            // ===== phase 1: q/k/v = W @ x  (12 m-tiles x 2 n-tiles, K=256) =====
            {
                const u16* Aq = wpk + (((size_t)(hg*64 + w*16 + l15)) << 8) + kg * 8;
                f32x4 cq0 = zf, cq1 = zf, ck0 = zf, ck1 = zf, cv0 = zf, cv1 = zf;
                #pragma unroll
                for (int ks = 0; ks < 8; ++ks){
                    bf16x8 b0 = *(const bf16x8*)&xs[((ks*4+kg)*32 + l15)*8];
                    bf16x8 b1 = *(const bf16x8*)&xs[((ks*4+kg)*32 + 16 + l15)*8];
                    bf16x8 a0 = *(const bf16x8*)(Aq + ks*32);
                    bf16x8 a1 = *(const bf16x8*)(Aq + 65536 + ks*32);
                    bf16x8 a2 = *(const bf16x8*)(Aq + 131072 + ks*32);
                    cq0 = MFMA(a0, b0, cq0); cq1 = MFMA(a0, b1, cq1);
                    ck0 = MFMA(a1, b0, ck0); ck1 = MFMA(a1, b1, ck1);
                    cv0 = MFMA(a2, b0, cv0); cv1 = MFMA(a2, b1, cv1);
                }
                const int hd0 = (w & 1) * 16 + kg * 4;      // C rows = hd0..hd0+3
                const int c0g = h * 32 + hd0;
                #pragma unroll
                for (int nt = 0; nt < 2; ++nt){
                    int node = nt * 16 + l15;
                    if (node < 25){
                        f32x4 q_ = nt ? cq1 : cq0;
                        f32x4 k_ = nt ? ck1 : ck0;
                        f32x4 v_ = nt ? cv1 : cv0;
                        uint2 qp; qp.x = pk2(q_[0], q_[1]); qp.y = pk2(q_[2], q_[3]);
                        *(uint2*)&qs[hl*1280 + node*40 + hd0] = qp;
                        uint2 ep = *(const uint2*)&es2[((c0g>>3)*26 + node)*8 + (c0g&7)];
                        float e0 = bf2f((u16)(ep.x & 0xFFFF)), e1 = bf2f((u16)(ep.x >> 16));
                        float e2 = bf2f((u16)(ep.y & 0xFFFF)), e3 = bf2f((u16)(ep.y >> 16));
                        uint2 kp; kp.x = pk2(k_[0]+e0, k_[1]+e1); kp.y = pk2(k_[2]+e2, k_[3]+e3);
                        *(uint2*)&ke[hl*1024 + ((hd0>>3)*32 + node)*8 + (hd0&7)] = kp;
                        vT[hl*1280 + (hd0+0)*40 + node] = f2bf(v_[0]);
                        vT[hl*1280 + (hd0+1)*40 + node] = f2bf(v_[1]);
                        vT[hl*1280 + (hd0+2)*40 + node] = f2bf(v_[2]);
                        vT[hl*1280 + (hd0+3)*40 + node] = f2bf(v_[3]);
                    }
                }
                // rpe -> ke cols 25-29 (already bf16 in wpk)
                for (int i = tid; i < 320; i += 256){
                    int hl2 = i / 160, rem = i % 160, j = rem >> 5, hd = rem & 31;
                    ke[hl2*1024 + ((hd>>3)*32 + 25 + j)*8 + (hd&7)] =
                        wpk[262144 + j*256 + (hg*2+hl2)*32 + hd];
                }
            }
            __syncthreads();

            // ===== scores: S = q @ (k+e | rpe)  (K=32) =====
            bf16x8 fq  = *(const bf16x8*)&qs[hl*1280 + (mt*16 + l15)*40 + kg*8];
            bf16x8 fk0 = *(const bf16x8*)&ke[hl*1024 + (kg*32 + l15)*8];
            bf16x8 fk1 = *(const bf16x8*)&ke[hl*1024 + (kg*32 + 16 + l15)*8];
            f32x4 s0 = MFMA(fq, fk0, zf);
            f32x4 s1 = MFMA(fq, fk1, zf);
            if ((w & 1) && lane < 25){      // group bias: w1 . e_k[b]
                const float* w1p = w1 + h * 32;
                float sb = 0.f;
                #pragma unroll
                for (int q8 = 0; q8 < 4; ++q8){
                    const u16* ep = &es2[((h*4 + q8)*26 + lane)*8];
                    #pragma unroll
                    for (int u = 0; u < 8; ++u) sb += bf2f(ep[u]) * w1p[q8*8 + u];
                }
                biasl[hl*32 + lane] = sb;
            }
            __syncthreads();

            // ===== softmax in-register (rows spread over 16-lane groups) =====
            {
                const int c0 = l15, c1 = 16 + l15;
                const bool val1 = (c1 < 25);
                const float b0f = biasl[hl*32 + c0];
                const float b1f = biasl[hl*32 + c1];
                float g0[4], g1[4];
                #pragma unroll
                for (int r = 0; r < 4; ++r){
                    const int a = mt*16 + kg*4 + r;
                    float rr0 = __shfl(s1[r], (lane & 48) + 9,  64);
                    float rr1 = __shfl(s1[r], (lane & 48) + 10, 64);
                    float rr2 = __shfl(s1[r], (lane & 48) + 11, 64);
                    float rr3 = __shfl(s1[r], (lane & 48) + 12, 64);
                    float rr4 = __shfl(s1[r], (lane & 48) + 13, 64);
                    int d0 = a - c0; d0 = d0 < 0 ? -d0 : d0; if (d0 > 4) d0 = 4;
                    int d1 = a - c1; d1 = d1 < 0 ? -d1 : d1; if (d1 > 4) d1 = 4;
                    float r0 = d0==0?rr0:d0==1?rr1:d0==2?rr2:d0==3?rr3:rr4;
                    float r1 = d1==0?rr0:d1==1?rr1:d1==2?rr2:d1==3?rr3:rr4;
                    float t0 = (s0[r] + r0 + b0f) * SCALE_;
                    float t1 = (s1[r] + r1 + b1f) * SCALE_;
                    float m = val1 ? fmaxf(t0, t1) : t0;
                    #pragma unroll
                    for (int msk = 1; msk < 16; msk <<= 1)
                        m = fmaxf(m, __shfl_xor(m, msk, 64));
                    float e0v = __expf(t0 - m);
                    float e1v = val1 ? __expf(t1 - m) : 0.f;
                    float sm = e0v + e1v;
                    #pragma unroll
                    for (int msk = 1; msk < 16; msk <<= 1)
                        sm += __shfl_xor(sm, msk, 64);
                    float inv = alpha0 / sm;
                    float o0v = 0.f, o1v = 0.f;
                    if (a < 25){
                        o0v = outer[(h*25 + a)*25 + c0];
                        if (val1) o1v = outer[(h*25 + a)*25 + c1];
                    }
                    g0[r] = e0v * inv + o0v;
                    g1[r] = val1 ? e1v * inv + o1v : 0.f;
                }
                #pragma unroll
                for (int r = 0; r < 4; ++r){
                    const int a = mt*16 + kg*4 + r;
                    GT[hl*1024 + ((c0>>3)*32 + a)*8 + (c0&7)] = f2bf(g0[r]);
                    GT[hl*1024 + ((c1>>3)*32 + a)*8 + (c1&7)] = f2bf(g1[r]);
                }
            }
            __syncthreads();

            // ===== PV: o^T[hd][a] = v^T @ G^T  (K=32, b-padded with zeros) =====
            {
                bf16x8 fv  = *(const bf16x8*)&vT[hl*1280 + (mt*16 + l15)*40 + kg*8];
                bf16x8 fg0 = *(const bf16x8*)&GT[hl*1024 + (kg*32 + l15)*8];
                bf16x8 fg1 = *(const bf16x8*)&GT[hl*1024 + (kg*32 + 16 + l15)*8];
                f32x4 o0 = MFMA(fv, fg0, zf);
                f32x4 o1 = MFMA(fv, fg1, zf);
                const int cp = hg*64 + hl*32 + mt*16 + kg*4;
                uint2 p; p.x = pk2(o0[0], o0[1]); p.y = pk2(o0[2], o0[3]);
                *(uint2*)&opk[((cp>>3)*32 + l15)*8 + (cp&7)] = p;
                if (l15 < 9){
                    uint2 p2; p2.x = pk2(o1[0], o1[1]); p2.y = pk2(o1[2], o1[3]);
                    *(uint2*)&opk[((cp>>3)*32 + 16 + l15)*8 + (cp&7)] = p2;
                }
            }
            __syncthreads();
        } // hg

        // ===== proj: out = Wproj @ o  (K=256) + bias =====
        {
            f32x4 pc[4][2];
            #pragma unroll
            for (int i = 0; i < 4; ++i){ pc[i][0] = zf; pc[i][1] = zf; }
            #pragma unroll
            for (int ks = 0; ks < 8; ++ks){
                bf16x8 pb0 = *(const bf16x8*)&opk[((ks*4+kg)*32 + l15)*8];
                bf16x8 pb1 = *(const bf16x8*)&opk[((ks*4+kg)*32 + 16 + l15)*8];
                #pragma unroll
                for (int i = 0; i < 4; ++i){
                    bf16x8 aw = *(const bf16x8*)(wpk +
                        (((size_t)(768 + w*64 + i*16 + l15)) << 8) + ks*32 + kg*8);
                    pc[i][0] = MFMA(aw, pb0, pc[i][0]);
                    pc[i][1] = MFMA(aw, pb1, pc[i][1]);
                }
            }
            #pragma unroll
            for (int i = 0; i < 4; ++i){
                const int d = w*64 + i*16 + kg*4;
                float bp0 = bproj[d], bp1 = bproj[d+1], bp2 = bproj[d+2], bp3 = bproj[d+3];
                #pragma unroll
                for (int nt = 0; nt < 2; ++nt){
                    int vv = nt*16 + l15;
                    if (vv < 25){
                        float* op = out + ((size_t)(n*256 + d)*120 + t)*25 + vv;
                        f32x4 cc = pc[i][nt];
                        op[0]    = cc[0] + bp0;
                        op[3000] = cc[1] + bp1;
                        op[6000] = cc[2] + bp2;
                        op[9000] = cc[3] + bp3;
                    }
                }
            }
        }
        __syncthreads();
    } // tl
}

extern "C" void kernel_launch(void* const* d_in, const int* in_sizes, int n_in,
                              void* d_out, int out_size, void* d_ws, size_t ws_size,
                              hipStream_t stream) {
    (void)in_sizes; (void)n_in; (void)out_size; (void)ws_size;
    const float* x     = (const float*)d_in[0];
    const float* e     = (const float*)d_in[1];
    const float* Wkv   = (const float*)d_in[2];
    const float* Wq    = (const float*)d_in[3];
    const float* Wproj = (const float*)d_in[4];
    const float* bproj = (const float*)d_in[5];
    const float* rpe   = (const float*)d_in[6];
    const float* w1    = (const float*)d_in[7];
    const float* outer = (const float*)d_in[8];
    const float* alpha = (const float*)d_in[9];
    float* out = (float*)d_out;
    u16* wpk = (u16*)d_ws;

    prep_kernel<<<1029, 256, 0, stream>>>(Wkv, Wq, Wproj, rpe, wpk);
    mhsa_main<<<32 * 30, 256, 0, stream>>>(x, e, w1, outer, alpha, bproj, wpk, out);
}